// Round 2
// baseline (85.932 us; speedup 1.0000x reference)
//
#include <hip/hip_runtime.h>

#define BB 8
#define TT 512
#define DD 64
#define S_SCALE 1.2011224087864498f   // sqrt(log2(e)); exp(-u^2) = exp2(-(S*u)^2)

typedef float v2f __attribute__((ext_vector_type(2)));

static __device__ __forceinline__ float fast_exp2(float v) {
#if __has_builtin(__builtin_amdgcn_exp2f)
    return __builtin_amdgcn_exp2f(v);
#else
    return exp2f(v);
#endif
}
static __device__ __forceinline__ float fast_rcp(float v) {
#if __has_builtin(__builtin_amdgcn_rcpf)
    return __builtin_amdgcn_rcpf(v);
#else
    return 1.0f / v;
#endif
}
static __device__ __forceinline__ v2f pk_fma(v2f a, v2f b, v2f c) {
#if __has_builtin(__builtin_elementwise_fma)
    return __builtin_elementwise_fma(a, b, c);
#else
    return a * b + c;
#endif
}

// ------- kernel 1: v = x@W^T + b ; writes f32 S*x and f32 v only -------
__global__ __launch_bounds__(256) void rbf_pre(
    const float* __restrict__ x, const float* __restrict__ W,
    const float* __restrict__ bias,
    float* __restrict__ xs, float* __restrict__ vv)
{
    const int t = threadIdx.x;
    const int w = t >> 6, l = t & 63;
    const int row = blockIdx.x * 4 + w;
    const float* xr = x + (size_t)row * DD;
    const float* wr = W + (size_t)l * DD;
    float acc = bias[l];
    #pragma unroll
    for (int d = 0; d < DD; d += 4) {
        float4 xv = *(const float4*)(xr + d);
        float4 wv = *(const float4*)(wr + d);
        acc = fmaf(xv.x, wv.x, acc); acc = fmaf(xv.y, wv.y, acc);
        acc = fmaf(xv.z, wv.z, acc); acc = fmaf(xv.w, wv.w, acc);
    }
    xs[(size_t)row * DD + l] = xr[l] * S_SCALE;
    vv[(size_t)row * DD + l] = acc;
}

// ------- tile body: 2 i-rows (per wave) x 64 j x 64 d, all f32, packed -------
// j-operands: dense ds_read_b128 from padded f32 LDS rows (stride 68 -> 2-way
// bank aliasing = free). i-operands: wave-uniform LDS broadcasts (b128).
// Inner body per 2 elements: pk_sub, pk_mul, 2x v_exp, 2x pk_fma, pk_add.
template <bool MIRROR>
static __device__ __forceinline__ void tile_compute(
    const float* xls, const float* vls,    // [64][68]
    const float* xis, const float* vis,    // [16][64]
    float* __restrict__ orow0, float* cbuf, int l, int wau)
{
    v2f nr[2][2], nc[2][2], dn[2][2];
    #pragma unroll
    for (int r = 0; r < 2; ++r) {
        nr[r][0] = (v2f){0.f, 0.f}; nr[r][1] = (v2f){0.f, 0.f};
        nc[r][0] = (v2f){0.f, 0.f}; nc[r][1] = (v2f){0.f, 0.f};
        dn[r][0] = (v2f){0.f, 0.f}; dn[r][1] = (v2f){0.f, 0.f};
    }

    #pragma unroll 4
    for (int c = 0; c < 16; ++c) {                 // 4 d-elements per step
        float4 xj4 = *(const float4*)(xls + l * 68 + c * 4);   // ds_read_b128
        float4 vj4 = *(const float4*)(vls + l * 68 + c * 4);
        const v2f* xjp = (const v2f*)&xj4;
        const v2f* vjp = (const v2f*)&vj4;
        #pragma unroll
        for (int r = 0; r < 2; ++r) {
            const v2f* xi2 = (const v2f*)(xis + (wau * 2 + r) * DD + c * 4); // bcast
            const v2f* vi2 = (const v2f*)(vis + (wau * 2 + r) * DD + c * 4); // bcast
            #pragma unroll
            for (int q = 0; q < 2; ++q) {
                v2f u = xi2[q] - xjp[q];
                u *= u;
                v2f e = {fast_exp2(-u.x), fast_exp2(-u.y)};
                nr[r][q] = pk_fma(e, vi2[q], nr[r][q]);
                if (MIRROR) nc[r][q] = pk_fma(e, vjp[q], nc[r][q]);
                dn[r][q] += e;
            }
        }
    }

    #pragma unroll
    for (int r = 0; r < 2; ++r) {
        v2f d2 = dn[r][0] + dn[r][1];
        float rd = fast_rcp(d2.x + d2.y);
        v2f sr = nr[r][0] + nr[r][1];
        orow0[(size_t)r * TT + l] = (sr.x + sr.y) * rd;   // coalesced 256 B
        if (MIRROR) {
            v2f sc = nc[r][0] + nc[r][1];
            cbuf[l * 20 + wau * 2 + r] = (sc.x + sc.y) * rd;
        }
    }
}

// ------- kernel 2: symmetric pairwise tiles, 16 i x 64 j, 144/batch -------
// idx<32: diagonal band (no mirror, 4 strips per 64x64 diag square);
// else triangle walk over 16-row bands strictly below the diagonal (mirror
// writes out[j, i0..i0+16) too). 512 threads = 8 waves x 2 i-rows.
__global__ __launch_bounds__(512, 4) void rbf_sym(
    const float* __restrict__ xs, const float* __restrict__ vv,
    float* __restrict__ out)
{
    const int bid = blockIdx.x;
    const int b = bid / 144;
    int idx = bid - b * 144;
    int ti, jt, isA;
    if (idx < 32) { jt = idx >> 2; ti = 4 * jt + (idx & 3); isA = 0; }
    else {
        int k = idx - 32, t = 1;
        while (k >= 4 * t) { k -= 4 * t; ++t; }   // <=6 scalar iters
        jt = t; ti = k; isA = 1;
    }
    const int i0 = ti * 16, j0 = jt * 64;

    const int tid = threadIdx.x;
    const int w = tid >> 6, l = tid & 63;
    const int wau = __builtin_amdgcn_readfirstlane(w);

    __shared__ __align__(16) float xls[64 * 68];   // f32 S*xj tile, 272 B rows
    __shared__ __align__(16) float vls[64 * 68];   // f32 vj tile
    __shared__ __align__(16) float xis[16 * DD];   // f32 S*xi strip (bcast reads)
    __shared__ __align__(16) float vis[16 * DD];   // f32 vi strip
    __shared__ __align__(16) float cbuf[64 * 20];  // mirror [j][iloc 0..15], pad 20

    // ---- stage j-tiles: 1024 float4 granules per array, 512 threads x 2 ----
    {
        const float4* xsrc = (const float4*)(xs + ((size_t)b * TT + j0) * DD);
        const float4* vsrc = (const float4*)(vv + ((size_t)b * TT + j0) * DD);
        #pragma unroll
        for (int k = 0; k < 2; ++k) {
            int g = k * 512 + tid;
            int r = g >> 4, c4 = (g & 15) * 4;
            *(float4*)(xls + r * 68 + c4) = xsrc[g];
            *(float4*)(vls + r * 68 + c4) = vsrc[g];
        }
        // ---- stage i-strips: 256 granules each; half the threads per array ----
        int g = tid & 255;
        int r = g >> 4, c4 = (g & 15) * 4;
        if (tid < 256)
            *(float4*)(xis + r * DD + c4) =
                *(const float4*)(xs + ((size_t)(b * TT + i0 + r)) * DD + c4);
        else
            *(float4*)(vis + r * DD + c4) =
                *(const float4*)(vv + ((size_t)(b * TT + i0 + r)) * DD + c4);
    }
    __syncthreads();

    float* outb  = out + (size_t)b * TT * TT;
    float* orow0 = outb + (size_t)(i0 + wau * 2) * TT + j0;

    if (isA) tile_compute<true >(xls, vls, xis, vis, orow0, cbuf, l, wau);
    else     tile_compute<false>(xls, vls, xis, vis, orow0, cbuf, l, wau);

    if (isA) {
        __syncthreads();
        if (tid < 256) {
            // flush mirror: out[j0+j][i0 .. i0+16), float4 per thread
            int j = tid >> 2, qf = (tid & 3) * 4;
            float4 cv = *(const float4*)(cbuf + j * 20 + qf);
            *(float4*)(outb + (size_t)(j0 + j) * TT + i0 + qf) = cv;
        }
    }
}

extern "C" void kernel_launch(void* const* d_in, const int* in_sizes, int n_in,
                              void* d_out, int out_size, void* d_ws, size_t ws_size,
                              hipStream_t stream) {
    const float* x    = (const float*)d_in[0];
    const float* W    = (const float*)d_in[1];
    const float* bias = (const float*)d_in[2];
    float* out        = (float*)d_out;

    float* xs = (float*)d_ws;                       // 1 MB f32 S*x
    float* vv = (float*)((char*)d_ws + (1 << 20));  // 1 MB f32 v

    rbf_pre<<<BB * TT / 4, 256, 0, stream>>>(x, W, bias, xs, vv);
    rbf_sym<<<BB * 144, 512, 0, stream>>>(xs, vv, out);
}